// Round 17
// baseline (416.991 us; speedup 1.0000x reference)
//
#include <hip/hip_runtime.h>
#include <hip/hip_bf16.h>

// GCN 2-layer forward on MI355X (gfx950).
// R17 (cleanup): dinv array + k_prep eliminated — rsqrtf(cnt+1) computed on
//      the fly in gemm epilogue/agg1/agg2 (all already touch cnt). w1t fused
//      into fillpad as disjoint blocks. 5 dispatches total.
//      Base = R16 (401us best).

#define NN 100000
#define NE 1600000
#define INC 768
#define HID 256
#define NCLS 8
#define DMAX 64
#define FILLB 6250  // NE/256
#define W1TB 768    // INC*HID/256

typedef short bf16x8 __attribute__((ext_vector_type(8)));
typedef float f32x4 __attribute__((ext_vector_type(4)));

__device__ __forceinline__ unsigned short f2bf(float f) {
  __hip_bfloat16 h = __float2bfloat16(f);
  return *reinterpret_cast<unsigned short*>(&h);
}
__device__ __forceinline__ float bf2f(unsigned short h) {
  return __uint_as_float(((unsigned int)h) << 16);
}

// ---------- fused: padded adjacency fill (blocks [0,FILLB)) + W1 transpose (rest) ----------
__global__ __launch_bounds__(256) void k_fillw(const int* __restrict__ ei,
                                               int* __restrict__ cnt,
                                               int* __restrict__ srcidx,
                                               const float* __restrict__ W1,
                                               unsigned short* __restrict__ w1t) {
  if (blockIdx.x < FILLB) {
    int e = blockIdx.x * 256 + threadIdx.x;
    if (e < NE) {
      int r = ei[e];         // source
      int c = ei[NE + e];    // target
      int slot = atomicAdd(&cnt[c], 1);
      if (slot < DMAX) srcidx[(long)c * DMAX + slot] = r;
    }
  } else {
    int t = (blockIdx.x - FILLB) * 256 + threadIdx.x;
    if (t < INC * HID) {
      int k = t / HID, n = t % HID;
      w1t[n * INC + k] = f2bf(W1[t]);
    }
  }
}

// raw barrier: drain LDS ops only; leave global loads in flight (no vmcnt(0))
#define BAR() asm volatile("s_waitcnt lgkmcnt(0)\n\ts_barrier" ::: "memory")

// ---------- GEMM1: h1s[NN][256] (bf16) = rsqrt(cnt+1) * (x @ W1) ----------
__global__ __launch_bounds__(512) void k_gemm1(const float* __restrict__ x,
                                               const unsigned short* __restrict__ w1t,
                                               const int* __restrict__ cnt,
                                               unsigned short* __restrict__ h1s) {
  __shared__ char smem[49152];
  unsigned short* As = (unsigned short*)smem;
  unsigned short* Bs = (unsigned short*)(smem + 16384);
  const int tid = threadIdx.x;
  const int lane = tid & 63;
  const int wid = tid >> 6;
  const int wm = wid >> 2;
  const int wn = wid & 3;
  const long bm = blockIdx.x;

  const int ar0 = tid >> 3, as7 = tid & 7;
  const int ar1 = (tid + 512) >> 3;
  long arow0 = bm * 128 + ar0; if (arow0 > NN - 1) arow0 = NN - 1;
  long arow1 = bm * 128 + ar1; if (arow1 > NN - 1) arow1 = NN - 1;
  const float* gA0 = x + arow0 * INC + as7 * 8;
  const float* gA1 = x + arow1 * INC + as7 * 8;
  const int aoff0 = (ar0 << 7) | ((as7 ^ (ar0 & 7)) << 4);
  const int aoff1 = (ar1 << 7) | ((as7 ^ (ar1 & 7)) << 4);

  f32x4 acc[4][4];
#pragma unroll
  for (int m = 0; m < 4; m++)
#pragma unroll
    for (int n = 0; n < 4; n++) acc[m][n] = (f32x4){0.f, 0.f, 0.f, 0.f};

  float4 Pa, Pb, Pc, Pd, Qa, Qb, Qc, Qd;
  uint4 rb0, rb1, rb2, rb3;

#define LOAD_ASET(Va, Vb, Vc, Vd, KT)             \
  do {                                            \
    Va = *(const float4*)(gA0 + (KT));            \
    Vb = *(const float4*)(gA0 + (KT) + 4);        \
    Vc = *(const float4*)(gA1 + (KT));            \
    Vd = *(const float4*)(gA1 + (KT) + 4);        \
  } while (0)
#define LOAD_B(KT)                                                                         \
  do {                                                                                     \
    rb0 = *(const uint4*)(w1t + (long)(tid >> 3) * INC + (KT) + (tid & 7) * 8);            \
    rb1 = *(const uint4*)(w1t + (long)((tid + 512) >> 3) * INC + (KT) + (tid & 7) * 8);    \
    rb2 = *(const uint4*)(w1t + (long)((tid + 1024) >> 3) * INC + (KT) + (tid & 7) * 8);   \
    rb3 = *(const uint4*)(w1t + (long)((tid + 1536) >> 3) * INC + (KT) + (tid & 7) * 8);   \
  } while (0)
#define WRITE_ASET(Va, Vb, Vc, Vd)                                                         \
  do {                                                                                     \
    union { unsigned short us[8]; uint4 v; } u;                                            \
    u.us[0] = f2bf(Va.x); u.us[1] = f2bf(Va.y); u.us[2] = f2bf(Va.z);                      \
    u.us[3] = f2bf(Va.w); u.us[4] = f2bf(Vb.x); u.us[5] = f2bf(Vb.y);                      \
    u.us[6] = f2bf(Vb.z); u.us[7] = f2bf(Vb.w);                                            \
    *(uint4*)((char*)As + aoff0) = u.v;                                                    \
    u.us[0] = f2bf(Vc.x); u.us[1] = f2bf(Vc.y); u.us[2] = f2bf(Vc.z);                      \
    u.us[3] = f2bf(Vc.w); u.us[4] = f2bf(Vd.x); u.us[5] = f2bf(Vd.y);                      \
    u.us[6] = f2bf(Vd.z); u.us[7] = f2bf(Vd.w);                                            \
    *(uint4*)((char*)As + aoff1) = u.v;                                                    \
  } while (0)
#define WRITE_B()                                                                          \
  do {                                                                                     \
    int r0 = tid >> 3, s7 = tid & 7;                                                       \
    *(uint4*)((char*)Bs + ((r0 << 7) | ((s7 ^ (r0 & 7)) << 4))) = rb0;                     \
    int r1 = (tid + 512) >> 3;                                                             \
    *(uint4*)((char*)Bs + ((r1 << 7) | ((s7 ^ (r1 & 7)) << 4))) = rb1;                     \
    int r2 = (tid + 1024) >> 3;                                                            \
    *(uint4*)((char*)Bs + ((r2 << 7) | ((s7 ^ (r2 & 7)) << 4))) = rb2;                     \
    int r3 = (tid + 1536) >> 3;                                                            \
    *(uint4*)((char*)Bs + ((r3 << 7) | ((s7 ^ (r3 & 7)) << 4))) = rb3;                     \
  } while (0)
#define MFMA_STEP()                                                                        \
  do {                                                                                     \
    _Pragma("unroll")                                                                      \
    for (int half = 0; half < 2; half++) {                                                 \
      bf16x8 af[4], bff[4];                                                                \
      int j = (half << 2) + (lane >> 4);                                                   \
      _Pragma("unroll")                                                                    \
      for (int m = 0; m < 4; m++) {                                                        \
        int row = wm * 64 + m * 16 + (lane & 15);                                          \
        af[m] = *(const bf16x8*)((const char*)As + ((row << 7) | ((j ^ (row & 7)) << 4))); \
      }                                                                                    \
      _Pragma("unroll")                                                                    \
      for (int n = 0; n < 4; n++) {                                                        \
        int row = wn * 64 + n * 16 + (lane & 15);                                          \
        bff[n] = *(const bf16x8*)((const char*)Bs + ((row << 7) | ((j ^ (row & 7)) << 4)));\
      }                                                                                    \
      _Pragma("unroll")                                                                    \
      for (int m = 0; m < 4; m++)                                                          \
        _Pragma("unroll")                                                                  \
        for (int n = 0; n < 4; n++)                                                        \
          acc[m][n] = __builtin_amdgcn_mfma_f32_16x16x32_bf16(af[m], bff[n], acc[m][n], 0, 0, 0); \
    }                                                                                      \
  } while (0)

  LOAD_ASET(Pa, Pb, Pc, Pd, 0);
  LOAD_B(0);
  LOAD_ASET(Qa, Qb, Qc, Qd, 64);

#pragma unroll 1
  for (int u = 0; u < 6; u++) {
    int kt = u * 128;
    WRITE_ASET(Pa, Pb, Pc, Pd);
    WRITE_B();
    BAR();
    if (kt + 64 < INC) LOAD_B(kt + 64);
    if (kt + 128 < INC) LOAD_ASET(Pa, Pb, Pc, Pd, kt + 128);
    MFMA_STEP();
    BAR();
    WRITE_ASET(Qa, Qb, Qc, Qd);
    WRITE_B();
    BAR();
    if (kt + 128 < INC) LOAD_B(kt + 128);
    if (kt + 192 < INC) LOAD_ASET(Qa, Qb, Qc, Qd, kt + 192);
    MFMA_STEP();
    BAR();
  }
#undef LOAD_ASET
#undef LOAD_B
#undef WRITE_ASET
#undef WRITE_B
#undef MFMA_STEP

  // epilogue: scale rows by rsqrt(cnt+1), stage in LDS, coalesced copy out
  unsigned short* Os = (unsigned short*)smem;  // [64][264]
#pragma unroll
  for (int chunk = 0; chunk < 2; chunk++) {
    if (wm == chunk) {
#pragma unroll
      for (int m = 0; m < 4; m++) {
        int grow0 = (int)(bm * 128) + chunk * 64 + m * 16 + ((lane >> 4) << 2);
        float dv[4];
#pragma unroll
        for (int r = 0; r < 4; r++) {
          int gr = grow0 + r;
          dv[r] = rsqrtf((float)cnt[gr < NN ? gr : NN - 1] + 1.0f);
        }
#pragma unroll
        for (int n = 0; n < 4; n++) {
          int lrow = m * 16 + ((lane >> 4) << 2);
          int lcol = wn * 64 + n * 16 + (lane & 15);
#pragma unroll
          for (int r = 0; r < 4; r++)
            Os[(lrow + r) * 264 + lcol] = f2bf(acc[m][n][r] * dv[r]);
        }
      }
    }
    __syncthreads();
    {
      int r = tid >> 3, s = tid & 7;
      long grow = bm * 128 + chunk * 64 + r;
      if (grow < NN) {
        unsigned short* dst = h1s + grow * HID;
#pragma unroll
        for (int i = 0; i < 4; i++) {
          int seg = s + i * 8;
          *(uint4*)(dst + seg * 8) = *(const uint4*)((const char*)Os + (long)r * 528 + seg * 16);
        }
      }
    }
    __syncthreads();
  }
}
#undef BAR

// ---------- agg1: pure gather-add over h1s, then di*(.)+b1, relu, W2; store h2s ----------
__global__ __launch_bounds__(256) void k_agg1(const unsigned short* __restrict__ h1s,
                                              const int* __restrict__ cnt,
                                              const int* __restrict__ srcidx,
                                              const float* __restrict__ b1,
                                              const float* __restrict__ W2,
                                              float* __restrict__ h2s) {
  int w = (int)((blockIdx.x * 256 + threadIdx.x) >> 6);
  int lane = threadIdx.x & 63;
  if (w >= NN) return;
  int cw = cnt[w];
  float di = rsqrtf((float)cw + 1.0f);
  int deg = cw > DMAX ? DMAX : cw;
  int c4 = lane << 2;
  const unsigned short* hb = h1s + c4;
  ushort4 hv = *(const ushort4*)(hb + (long)w * HID);
  float a0 = bf2f(hv.x), a1 = bf2f(hv.y), a2 = bf2f(hv.z), a3 = bf2f(hv.w);
  const int* sr = srcidx + (long)w * DMAX;
  int e = 0;
  for (; e + 8 <= deg; e += 8) {
    int4 s0 = *(const int4*)(sr + e);
    int4 s1 = *(const int4*)(sr + e + 4);
    ushort4 g0 = *(const ushort4*)(hb + (long)s0.x * HID);
    ushort4 g1 = *(const ushort4*)(hb + (long)s0.y * HID);
    ushort4 g2 = *(const ushort4*)(hb + (long)s0.z * HID);
    ushort4 g3 = *(const ushort4*)(hb + (long)s0.w * HID);
    ushort4 g4 = *(const ushort4*)(hb + (long)s1.x * HID);
    ushort4 g5 = *(const ushort4*)(hb + (long)s1.y * HID);
    ushort4 g6 = *(const ushort4*)(hb + (long)s1.z * HID);
    ushort4 g7 = *(const ushort4*)(hb + (long)s1.w * HID);
    a0 += bf2f(g0.x) + bf2f(g1.x) + bf2f(g2.x) + bf2f(g3.x) +
          bf2f(g4.x) + bf2f(g5.x) + bf2f(g6.x) + bf2f(g7.x);
    a1 += bf2f(g0.y) + bf2f(g1.y) + bf2f(g2.y) + bf2f(g3.y) +
          bf2f(g4.y) + bf2f(g5.y) + bf2f(g6.y) + bf2f(g7.y);
    a2 += bf2f(g0.z) + bf2f(g1.z) + bf2f(g2.z) + bf2f(g3.z) +
          bf2f(g4.z) + bf2f(g5.z) + bf2f(g6.z) + bf2f(g7.z);
    a3 += bf2f(g0.w) + bf2f(g1.w) + bf2f(g2.w) + bf2f(g3.w) +
          bf2f(g4.w) + bf2f(g5.w) + bf2f(g6.w) + bf2f(g7.w);
  }
  for (; e < deg; e++) {
    int src = sr[e];
    ushort4 g = *(const ushort4*)(hb + (long)src * HID);
    a0 += bf2f(g.x); a1 += bf2f(g.y);
    a2 += bf2f(g.z); a3 += bf2f(g.w);
  }
  float4 bv = *(const float4*)(b1 + c4);
  float v0 = di * a0 + bv.x; v0 = v0 > 0.f ? v0 : 0.f;
  float v1 = di * a1 + bv.y; v1 = v1 > 0.f ? v1 : 0.f;
  float v2 = di * a2 + bv.z; v2 = v2 > 0.f ? v2 : 0.f;
  float v3 = di * a3 + bv.w; v3 = v3 > 0.f ? v3 : 0.f;
  const float4* wp = (const float4*)(W2 + ((long)c4 << 3));
  float4 r0a = wp[0], r0b = wp[1], r1a = wp[2], r1b = wp[3];
  float4 r2a = wp[4], r2b = wp[5], r3a = wp[6], r3b = wp[7];
  float p[8];
  p[0] = v0 * r0a.x + v1 * r1a.x + v2 * r2a.x + v3 * r3a.x;
  p[1] = v0 * r0a.y + v1 * r1a.y + v2 * r2a.y + v3 * r3a.y;
  p[2] = v0 * r0a.z + v1 * r1a.z + v2 * r2a.z + v3 * r3a.z;
  p[3] = v0 * r0a.w + v1 * r1a.w + v2 * r2a.w + v3 * r3a.w;
  p[4] = v0 * r0b.x + v1 * r1b.x + v2 * r2b.x + v3 * r3b.x;
  p[5] = v0 * r0b.y + v1 * r1b.y + v2 * r2b.y + v3 * r3b.y;
  p[6] = v0 * r0b.z + v1 * r1b.z + v2 * r2b.z + v3 * r3b.z;
  p[7] = v0 * r0b.w + v1 * r1b.w + v2 * r2b.w + v3 * r3b.w;
#pragma unroll
  for (int c = 0; c < 8; c++)
#pragma unroll
    for (int off = 1; off < 64; off <<= 1) p[c] += __shfl_xor(p[c], off, 64);
  if (lane < 8) {
    float o = p[0];
    o = (lane == 1) ? p[1] : o;
    o = (lane == 2) ? p[2] : o;
    o = (lane == 3) ? p[3] : o;
    o = (lane == 4) ? p[4] : o;
    o = (lane == 5) ? p[5] : o;
    o = (lane == 6) ? p[6] : o;
    o = (lane == 7) ? p[7] : o;
    h2s[(long)w * NCLS + lane] = di * o;  // pre-scaled for agg2
  }
}

// ---------- agg2: out = di * (h2s[self] + sum h2s[src]) + b2 ----------
__global__ __launch_bounds__(256) void k_agg2(const float* __restrict__ h2s,
                                              const int* __restrict__ cnt,
                                              const int* __restrict__ srcidx,
                                              const float* __restrict__ b2,
                                              float* __restrict__ out) {
  long t = (long)blockIdx.x * 256 + threadIdx.x;
  long i = t >> 3;
  int c = (int)(t & 7);
  if (i >= NN) return;
  int ci = cnt[i];
  float di = rsqrtf((float)ci + 1.0f);
  int deg = ci > DMAX ? DMAX : ci;
  float s = h2s[i * NCLS + c];
  const int* sr = srcidx + i * DMAX;
  int e = 0;
  for (; e + 8 <= deg; e += 8) {
    int4 s0 = *(const int4*)(sr + e);
    int4 s1 = *(const int4*)(sr + e + 4);
    float g0 = h2s[(long)s0.x * NCLS + c], g1 = h2s[(long)s0.y * NCLS + c];
    float g2 = h2s[(long)s0.z * NCLS + c], g3 = h2s[(long)s0.w * NCLS + c];
    float g4 = h2s[(long)s1.x * NCLS + c], g5 = h2s[(long)s1.y * NCLS + c];
    float g6 = h2s[(long)s1.z * NCLS + c], g7 = h2s[(long)s1.w * NCLS + c];
    s += g0 + g1 + g2 + g3 + g4 + g5 + g6 + g7;
  }
  for (; e < deg; e++) {
    s += h2s[(long)sr[e] * NCLS + c];
  }
  out[i * NCLS + c] = di * s + b2[c];
}

extern "C" void kernel_launch(void* const* d_in, const int* in_sizes, int n_in,
                              void* d_out, int out_size, void* d_ws, size_t ws_size,
                              hipStream_t stream) {
  (void)in_sizes; (void)n_in; (void)out_size; (void)ws_size;
  const float* x  = (const float*)d_in[0];
  const int*   ei = (const int*)d_in[1];
  const float* W1 = (const float*)d_in[2];
  const float* b1 = (const float*)d_in[3];
  const float* W2 = (const float*)d_in[4];
  const float* b2 = (const float*)d_in[5];
  float* out = (float*)d_out;
  char* ws = (char*)d_ws;

  unsigned short* h1s  = (unsigned short*)(ws + 0L);          // 51,200,000
  float* h2s           = (float*)(ws + 51200000L);            // 3,200,000
  int*   cnt           = (int*)(ws + 54400000L);              // 400,000
  int*   srcidx        = (int*)(ws + 54800000L);              // 25,600,000 (padded [NN][64])
  unsigned short* w1t  = (unsigned short*)(ws + 80400000L);   // 393,216

  hipMemsetAsync(cnt, 0, NN * sizeof(int), stream);
  k_fillw<<<FILLB + W1TB, 256, 0, stream>>>(ei, cnt, srcidx, W1, w1t);
  k_gemm1<<<782, 512, 0, stream>>>(x, w1t, cnt, h1s);
  k_agg1<<<(NN * 64 + 255) / 256, 256, 0, stream>>>(h1s, cnt, srcidx, b1, W2, h2s);
  k_agg2<<<(NN * NCLS + 255) / 256, 256, 0, stream>>>(h2s, cnt, srcidx, b2, out);
}

// Round 18
// 397.640 us; speedup vs baseline: 1.0487x; 1.0487x over previous
//
#include <hip/hip_runtime.h>
#include <hip/hip_bf16.h>

// GCN 2-layer forward on MI355X (gfx950).
// R18 = exact revert to R16 (best: 401.3us). R17's cleanup (dinv removal +
// w1t-into-fillpad fusion) regressed to 417us — scatter/scatter residency
// sharing + duplicated rsqrt streams. Final configuration:
//   memset -> fillpad(atomic slots) -> prep(dinv+w1t) -> gemm1(bf16 MFMA,
//   no-vmcnt-drain barriers, pre-scaled h1s) -> agg1(gather-add + relu+W2,
//   pre-scaled h2s) -> agg2(gather-add).

#define NN 100000
#define NE 1600000
#define INC 768
#define HID 256
#define NCLS 8
#define DMAX 64
#define DINVB 391   // ceil(NN/256)
#define W1TB 768    // INC*HID/256

typedef short bf16x8 __attribute__((ext_vector_type(8)));
typedef float f32x4 __attribute__((ext_vector_type(4)));

__device__ __forceinline__ unsigned short f2bf(float f) {
  __hip_bfloat16 h = __float2bfloat16(f);
  return *reinterpret_cast<unsigned short*>(&h);
}
__device__ __forceinline__ float bf2f(unsigned short h) {
  return __uint_as_float(((unsigned int)h) << 16);
}

// ---------- padded adjacency fill: one atomic pass gives slots AND counts ----------
__global__ __launch_bounds__(256) void k_fillpad(const int* __restrict__ ei,
                                                 int* __restrict__ cnt,
                                                 int* __restrict__ srcidx) {
  int e = blockIdx.x * 256 + threadIdx.x;
  if (e >= NE) return;
  int r = ei[e];         // source
  int c = ei[NE + e];    // target
  int slot = atomicAdd(&cnt[c], 1);
  if (slot < DMAX) srcidx[(long)c * DMAX + slot] = r;
}

// ---------- prep: dinv (blocks [0,DINVB)) + W1 transpose/cast (blocks [DINVB,..)) ----------
__global__ __launch_bounds__(256) void k_prep(const int* __restrict__ cnt, float* __restrict__ dinv,
                                              const float* __restrict__ W1, unsigned short* __restrict__ w1t) {
  if (blockIdx.x < DINVB) {
    int i = blockIdx.x * 256 + threadIdx.x;
    if (i < NN) dinv[i] = rsqrtf((float)cnt[i] + 1.0f);  // +1 self-loop
  } else {
    int t = (blockIdx.x - DINVB) * 256 + threadIdx.x;
    if (t < INC * HID) {
      int k = t / HID, n = t % HID;
      w1t[n * INC + k] = f2bf(W1[t]);
    }
  }
}

// raw barrier: drain LDS ops only; leave global loads in flight (no vmcnt(0))
#define BAR() asm volatile("s_waitcnt lgkmcnt(0)\n\ts_barrier" ::: "memory")

// ---------- GEMM1: h1s[NN][256] (bf16) = dinv * (x @ W1) ----------
__global__ __launch_bounds__(512) void k_gemm1(const float* __restrict__ x,
                                               const unsigned short* __restrict__ w1t,
                                               const float* __restrict__ dinv,
                                               unsigned short* __restrict__ h1s) {
  __shared__ char smem[49152];
  unsigned short* As = (unsigned short*)smem;
  unsigned short* Bs = (unsigned short*)(smem + 16384);
  const int tid = threadIdx.x;
  const int lane = tid & 63;
  const int wid = tid >> 6;
  const int wm = wid >> 2;
  const int wn = wid & 3;
  const long bm = blockIdx.x;

  const int ar0 = tid >> 3, as7 = tid & 7;
  const int ar1 = (tid + 512) >> 3;
  long arow0 = bm * 128 + ar0; if (arow0 > NN - 1) arow0 = NN - 1;
  long arow1 = bm * 128 + ar1; if (arow1 > NN - 1) arow1 = NN - 1;
  const float* gA0 = x + arow0 * INC + as7 * 8;
  const float* gA1 = x + arow1 * INC + as7 * 8;
  const int aoff0 = (ar0 << 7) | ((as7 ^ (ar0 & 7)) << 4);
  const int aoff1 = (ar1 << 7) | ((as7 ^ (ar1 & 7)) << 4);

  f32x4 acc[4][4];
#pragma unroll
  for (int m = 0; m < 4; m++)
#pragma unroll
    for (int n = 0; n < 4; n++) acc[m][n] = (f32x4){0.f, 0.f, 0.f, 0.f};

  float4 Pa, Pb, Pc, Pd, Qa, Qb, Qc, Qd;
  uint4 rb0, rb1, rb2, rb3;

#define LOAD_ASET(Va, Vb, Vc, Vd, KT)             \
  do {                                            \
    Va = *(const float4*)(gA0 + (KT));            \
    Vb = *(const float4*)(gA0 + (KT) + 4);        \
    Vc = *(const float4*)(gA1 + (KT));            \
    Vd = *(const float4*)(gA1 + (KT) + 4);        \
  } while (0)
#define LOAD_B(KT)                                                                         \
  do {                                                                                     \
    rb0 = *(const uint4*)(w1t + (long)(tid >> 3) * INC + (KT) + (tid & 7) * 8);            \
    rb1 = *(const uint4*)(w1t + (long)((tid + 512) >> 3) * INC + (KT) + (tid & 7) * 8);    \
    rb2 = *(const uint4*)(w1t + (long)((tid + 1024) >> 3) * INC + (KT) + (tid & 7) * 8);   \
    rb3 = *(const uint4*)(w1t + (long)((tid + 1536) >> 3) * INC + (KT) + (tid & 7) * 8);   \
  } while (0)
#define WRITE_ASET(Va, Vb, Vc, Vd)                                                         \
  do {                                                                                     \
    union { unsigned short us[8]; uint4 v; } u;                                            \
    u.us[0] = f2bf(Va.x); u.us[1] = f2bf(Va.y); u.us[2] = f2bf(Va.z);                      \
    u.us[3] = f2bf(Va.w); u.us[4] = f2bf(Vb.x); u.us[5] = f2bf(Vb.y);                      \
    u.us[6] = f2bf(Vb.z); u.us[7] = f2bf(Vb.w);                                            \
    *(uint4*)((char*)As + aoff0) = u.v;                                                    \
    u.us[0] = f2bf(Vc.x); u.us[1] = f2bf(Vc.y); u.us[2] = f2bf(Vc.z);                      \
    u.us[3] = f2bf(Vc.w); u.us[4] = f2bf(Vd.x); u.us[5] = f2bf(Vd.y);                      \
    u.us[6] = f2bf(Vd.z); u.us[7] = f2bf(Vd.w);                                            \
    *(uint4*)((char*)As + aoff1) = u.v;                                                    \
  } while (0)
#define WRITE_B()                                                                          \
  do {                                                                                     \
    int r0 = tid >> 3, s7 = tid & 7;                                                       \
    *(uint4*)((char*)Bs + ((r0 << 7) | ((s7 ^ (r0 & 7)) << 4))) = rb0;                     \
    int r1 = (tid + 512) >> 3;                                                             \
    *(uint4*)((char*)Bs + ((r1 << 7) | ((s7 ^ (r1 & 7)) << 4))) = rb1;                     \
    int r2 = (tid + 1024) >> 3;                                                            \
    *(uint4*)((char*)Bs + ((r2 << 7) | ((s7 ^ (r2 & 7)) << 4))) = rb2;                     \
    int r3 = (tid + 1536) >> 3;                                                            \
    *(uint4*)((char*)Bs + ((r3 << 7) | ((s7 ^ (r3 & 7)) << 4))) = rb3;                     \
  } while (0)
#define MFMA_STEP()                                                                        \
  do {                                                                                     \
    _Pragma("unroll")                                                                      \
    for (int half = 0; half < 2; half++) {                                                 \
      bf16x8 af[4], bff[4];                                                                \
      int j = (half << 2) + (lane >> 4);                                                   \
      _Pragma("unroll")                                                                    \
      for (int m = 0; m < 4; m++) {                                                        \
        int row = wm * 64 + m * 16 + (lane & 15);                                          \
        af[m] = *(const bf16x8*)((const char*)As + ((row << 7) | ((j ^ (row & 7)) << 4))); \
      }                                                                                    \
      _Pragma("unroll")                                                                    \
      for (int n = 0; n < 4; n++) {                                                        \
        int row = wn * 64 + n * 16 + (lane & 15);                                          \
        bff[n] = *(const bf16x8*)((const char*)Bs + ((row << 7) | ((j ^ (row & 7)) << 4)));\
      }                                                                                    \
      _Pragma("unroll")                                                                    \
      for (int m = 0; m < 4; m++)                                                          \
        _Pragma("unroll")                                                                  \
        for (int n = 0; n < 4; n++)                                                        \
          acc[m][n] = __builtin_amdgcn_mfma_f32_16x16x32_bf16(af[m], bff[n], acc[m][n], 0, 0, 0); \
    }                                                                                      \
  } while (0)

  LOAD_ASET(Pa, Pb, Pc, Pd, 0);
  LOAD_B(0);
  LOAD_ASET(Qa, Qb, Qc, Qd, 64);

#pragma unroll 1
  for (int u = 0; u < 6; u++) {
    int kt = u * 128;
    WRITE_ASET(Pa, Pb, Pc, Pd);   // waits only its own A@kt loads (counted)
    WRITE_B();
    BAR();                        // LDS drain + barrier; later loads stay in flight
    if (kt + 64 < INC) LOAD_B(kt + 64);
    if (kt + 128 < INC) LOAD_ASET(Pa, Pb, Pc, Pd, kt + 128);
    MFMA_STEP();
    BAR();
    WRITE_ASET(Qa, Qb, Qc, Qd);
    WRITE_B();
    BAR();
    if (kt + 128 < INC) LOAD_B(kt + 128);
    if (kt + 192 < INC) LOAD_ASET(Qa, Qb, Qc, Qd, kt + 192);
    MFMA_STEP();
    BAR();
  }
#undef LOAD_ASET
#undef LOAD_B
#undef WRITE_ASET
#undef WRITE_B
#undef MFMA_STEP

  // epilogue: scale rows by dinv, stage in LDS, coalesced copy out
  unsigned short* Os = (unsigned short*)smem;  // [64][264]
#pragma unroll
  for (int chunk = 0; chunk < 2; chunk++) {
    if (wm == chunk) {
#pragma unroll
      for (int m = 0; m < 4; m++) {
        int grow0 = (int)(bm * 128) + chunk * 64 + m * 16 + ((lane >> 4) << 2);
        float dv[4];
#pragma unroll
        for (int r = 0; r < 4; r++) {
          int gr = grow0 + r;
          dv[r] = dinv[gr < NN ? gr : NN - 1];
        }
#pragma unroll
        for (int n = 0; n < 4; n++) {
          int lrow = m * 16 + ((lane >> 4) << 2);
          int lcol = wn * 64 + n * 16 + (lane & 15);
#pragma unroll
          for (int r = 0; r < 4; r++)
            Os[(lrow + r) * 264 + lcol] = f2bf(acc[m][n][r] * dv[r]);
        }
      }
    }
    __syncthreads();
    {
      int r = tid >> 3, s = tid & 7;
      long grow = bm * 128 + chunk * 64 + r;
      if (grow < NN) {
        unsigned short* dst = h1s + grow * HID;
#pragma unroll
        for (int i = 0; i < 4; i++) {
          int seg = s + i * 8;
          *(uint4*)(dst + seg * 8) = *(const uint4*)((const char*)Os + (long)r * 528 + seg * 16);
        }
      }
    }
    __syncthreads();
  }
}
#undef BAR

// ---------- agg1: pure gather-add over h1s, then di*(.)+b1, relu, W2; store h2s ----------
__global__ __launch_bounds__(256) void k_agg1(const unsigned short* __restrict__ h1s,
                                              const float* __restrict__ dinv,
                                              const int* __restrict__ cnt,
                                              const int* __restrict__ srcidx,
                                              const float* __restrict__ b1,
                                              const float* __restrict__ W2,
                                              float* __restrict__ h2s) {
  int w = (int)((blockIdx.x * 256 + threadIdx.x) >> 6);
  int lane = threadIdx.x & 63;
  if (w >= NN) return;
  float di = dinv[w];
  int c4 = lane << 2;
  const unsigned short* hb = h1s + c4;
  ushort4 hv = *(const ushort4*)(hb + (long)w * HID);
  float a0 = bf2f(hv.x), a1 = bf2f(hv.y), a2 = bf2f(hv.z), a3 = bf2f(hv.w);
  int deg = cnt[w];
  if (deg > DMAX) deg = DMAX;
  const int* sr = srcidx + (long)w * DMAX;
  int e = 0;
  for (; e + 8 <= deg; e += 8) {
    int4 s0 = *(const int4*)(sr + e);
    int4 s1 = *(const int4*)(sr + e + 4);
    ushort4 g0 = *(const ushort4*)(hb + (long)s0.x * HID);
    ushort4 g1 = *(const ushort4*)(hb + (long)s0.y * HID);
    ushort4 g2 = *(const ushort4*)(hb + (long)s0.z * HID);
    ushort4 g3 = *(const ushort4*)(hb + (long)s0.w * HID);
    ushort4 g4 = *(const ushort4*)(hb + (long)s1.x * HID);
    ushort4 g5 = *(const ushort4*)(hb + (long)s1.y * HID);
    ushort4 g6 = *(const ushort4*)(hb + (long)s1.z * HID);
    ushort4 g7 = *(const ushort4*)(hb + (long)s1.w * HID);
    a0 += bf2f(g0.x) + bf2f(g1.x) + bf2f(g2.x) + bf2f(g3.x) +
          bf2f(g4.x) + bf2f(g5.x) + bf2f(g6.x) + bf2f(g7.x);
    a1 += bf2f(g0.y) + bf2f(g1.y) + bf2f(g2.y) + bf2f(g3.y) +
          bf2f(g4.y) + bf2f(g5.y) + bf2f(g6.y) + bf2f(g7.y);
    a2 += bf2f(g0.z) + bf2f(g1.z) + bf2f(g2.z) + bf2f(g3.z) +
          bf2f(g4.z) + bf2f(g5.z) + bf2f(g6.z) + bf2f(g7.z);
    a3 += bf2f(g0.w) + bf2f(g1.w) + bf2f(g2.w) + bf2f(g3.w) +
          bf2f(g4.w) + bf2f(g5.w) + bf2f(g6.w) + bf2f(g7.w);
  }
  for (; e < deg; e++) {
    int src = sr[e];
    ushort4 g = *(const ushort4*)(hb + (long)src * HID);
    a0 += bf2f(g.x); a1 += bf2f(g.y);
    a2 += bf2f(g.z); a3 += bf2f(g.w);
  }
  float4 bv = *(const float4*)(b1 + c4);
  float v0 = di * a0 + bv.x; v0 = v0 > 0.f ? v0 : 0.f;
  float v1 = di * a1 + bv.y; v1 = v1 > 0.f ? v1 : 0.f;
  float v2 = di * a2 + bv.z; v2 = v2 > 0.f ? v2 : 0.f;
  float v3 = di * a3 + bv.w; v3 = v3 > 0.f ? v3 : 0.f;
  const float4* wp = (const float4*)(W2 + ((long)c4 << 3));
  float4 r0a = wp[0], r0b = wp[1], r1a = wp[2], r1b = wp[3];
  float4 r2a = wp[4], r2b = wp[5], r3a = wp[6], r3b = wp[7];
  float p[8];
  p[0] = v0 * r0a.x + v1 * r1a.x + v2 * r2a.x + v3 * r3a.x;
  p[1] = v0 * r0a.y + v1 * r1a.y + v2 * r2a.y + v3 * r3a.y;
  p[2] = v0 * r0a.z + v1 * r1a.z + v2 * r2a.z + v3 * r3a.z;
  p[3] = v0 * r0a.w + v1 * r1a.w + v2 * r2a.w + v3 * r3a.w;
  p[4] = v0 * r0b.x + v1 * r1b.x + v2 * r2b.x + v3 * r3b.x;
  p[5] = v0 * r0b.y + v1 * r1b.y + v2 * r2b.y + v3 * r3b.y;
  p[6] = v0 * r0b.z + v1 * r1b.z + v2 * r2b.z + v3 * r3b.z;
  p[7] = v0 * r0b.w + v1 * r1b.w + v2 * r2b.w + v3 * r3b.w;
#pragma unroll
  for (int c = 0; c < 8; c++)
#pragma unroll
    for (int off = 1; off < 64; off <<= 1) p[c] += __shfl_xor(p[c], off, 64);
  if (lane < 8) {
    float o = p[0];
    o = (lane == 1) ? p[1] : o;
    o = (lane == 2) ? p[2] : o;
    o = (lane == 3) ? p[3] : o;
    o = (lane == 4) ? p[4] : o;
    o = (lane == 5) ? p[5] : o;
    o = (lane == 6) ? p[6] : o;
    o = (lane == 7) ? p[7] : o;
    h2s[(long)w * NCLS + lane] = di * o;  // pre-scaled for agg2
  }
}

// ---------- agg2: out = di * (h2s[self] + sum h2s[src]) + b2 ----------
__global__ __launch_bounds__(256) void k_agg2(const float* __restrict__ h2s,
                                              const float* __restrict__ dinv,
                                              const int* __restrict__ cnt,
                                              const int* __restrict__ srcidx,
                                              const float* __restrict__ b2,
                                              float* __restrict__ out) {
  long t = (long)blockIdx.x * 256 + threadIdx.x;
  long i = t >> 3;
  int c = (int)(t & 7);
  if (i >= NN) return;
  float di = dinv[i];
  float s = h2s[i * NCLS + c];
  int deg = cnt[i];
  if (deg > DMAX) deg = DMAX;
  const int* sr = srcidx + i * DMAX;
  int e = 0;
  for (; e + 8 <= deg; e += 8) {
    int4 s0 = *(const int4*)(sr + e);
    int4 s1 = *(const int4*)(sr + e + 4);
    float g0 = h2s[(long)s0.x * NCLS + c], g1 = h2s[(long)s0.y * NCLS + c];
    float g2 = h2s[(long)s0.z * NCLS + c], g3 = h2s[(long)s0.w * NCLS + c];
    float g4 = h2s[(long)s1.x * NCLS + c], g5 = h2s[(long)s1.y * NCLS + c];
    float g6 = h2s[(long)s1.z * NCLS + c], g7 = h2s[(long)s1.w * NCLS + c];
    s += g0 + g1 + g2 + g3 + g4 + g5 + g6 + g7;
  }
  for (; e < deg; e++) {
    s += h2s[(long)sr[e] * NCLS + c];
  }
  out[i * NCLS + c] = di * s + b2[c];
}

extern "C" void kernel_launch(void* const* d_in, const int* in_sizes, int n_in,
                              void* d_out, int out_size, void* d_ws, size_t ws_size,
                              hipStream_t stream) {
  (void)in_sizes; (void)n_in; (void)out_size; (void)ws_size;
  const float* x  = (const float*)d_in[0];
  const int*   ei = (const int*)d_in[1];
  const float* W1 = (const float*)d_in[2];
  const float* b1 = (const float*)d_in[3];
  const float* W2 = (const float*)d_in[4];
  const float* b2 = (const float*)d_in[5];
  float* out = (float*)d_out;
  char* ws = (char*)d_ws;

  unsigned short* h1s  = (unsigned short*)(ws + 0L);          // 51,200,000
  float* h2s           = (float*)(ws + 51200000L);            // 3,200,000
  float* dinv          = (float*)(ws + 54400000L);            // 400,000
  int*   cnt           = (int*)(ws + 54800000L);              // 400,000
  int*   srcidx        = (int*)(ws + 55200000L);              // 25,600,000 (padded [NN][64])
  unsigned short* w1t  = (unsigned short*)(ws + 80800000L);   // 393,216

  hipMemsetAsync(cnt, 0, NN * sizeof(int), stream);
  k_fillpad<<<(NE + 255) / 256, 256, 0, stream>>>(ei, cnt, srcidx);
  k_prep<<<DINVB + W1TB, 256, 0, stream>>>(cnt, dinv, W1, w1t);
  k_gemm1<<<782, 512, 0, stream>>>(x, w1t, dinv, h1s);
  k_agg1<<<(NN * 64 + 255) / 256, 256, 0, stream>>>(h1s, dinv, cnt, srcidx, b1, W2, h2s);
  k_agg2<<<(NN * NCLS + 255) / 256, 256, 0, stream>>>(h2s, dinv, cnt, srcidx, b2, out);
}